// Round 1
// baseline (105.260 us; speedup 1.0000x reference)
//
#include <hip/hip_runtime.h>
#include <math.h>

#define B_DIM 512
#define T_DIM 256
#define C_DIM 400
#define EPSV 1e-8f

// ---------------------------------------------------------------------------
// Kernel 1: per-(b,t) row softmax stats: m = max_c x, s = sum_c exp(x - m)
// One wave (64 lanes) per row; 4 rows per 256-thread block.
// ---------------------------------------------------------------------------
__global__ __launch_bounds__(256) void row_stats_kernel(
    const float* __restrict__ x, float* __restrict__ rmax, float* __restrict__ rsum) {
    int row  = blockIdx.x * 4 + (threadIdx.x >> 6);   // row = b*T + t
    int lane = threadIdx.x & 63;
    const float* xr = x + (size_t)row * C_DIM;

    float v[7];
    float m = -INFINITY;
    #pragma unroll
    for (int k = 0; k < 7; ++k) {
        int c = lane + k * 64;
        v[k] = (c < C_DIM) ? xr[c] : -INFINITY;
        m = fmaxf(m, v[k]);
    }
    #pragma unroll
    for (int off = 32; off > 0; off >>= 1)
        m = fmaxf(m, __shfl_xor(m, off, 64));

    float s = 0.f;
    #pragma unroll
    for (int k = 0; k < 7; ++k) {
        int c = lane + k * 64;
        if (c < C_DIM) s += expf(v[k] - m);
    }
    #pragma unroll
    for (int off = 32; off > 0; off >>= 1)
        s += __shfl_xor(s, off, 64);

    if (lane == 0) { rmax[row] = m; rsum[row] = s; }
}

// ---------------------------------------------------------------------------
// Kernel 2: per-(b,c) scan over t: running max (cummax), first argmax,
// sum of cummax (double accumulator). Writes idx, max_probs, e_x.
// Block = 256 threads; 2 blocks per b cover c in [0,256) and [256,400).
// ---------------------------------------------------------------------------
__global__ __launch_bounds__(256) void time_scan_kernel(
    const float* __restrict__ x, const float* __restrict__ rmax,
    const float* __restrict__ rsum, float* __restrict__ out) {
    __shared__ float rm_s[T_DIM];
    __shared__ float rs_s[T_DIM];

    int b     = blockIdx.x >> 1;
    int cbase = (blockIdx.x & 1) << 8;
    int tid   = threadIdx.x;

    // T_DIM == blockDim.x: each thread stages one row-stat pair
    rm_s[tid] = rmax[b * T_DIM + tid];
    rs_s[tid] = rsum[b * T_DIM + tid];
    __syncthreads();

    int c = cbase + tid;
    if (c >= C_DIM) return;

    const float* xb = x + (size_t)b * T_DIM * C_DIM + c;

    float  cur = -1.0f;   // running max of clamped proba (proba > 0 always)
    int    arg = 0;       // first index achieving the running max
    double scm = 0.0;     // sum of cummax over t (double: avoids cancellation in e_x)

    for (int t = 0; t < T_DIM; ++t) {
        float p = expf(xb[(size_t)t * C_DIM] - rm_s[t]) / rs_s[t];
        p = fmaxf(p, EPSV);
        if (p > cur) { cur = p; arg = t; }
        scm += (double)cur;
    }

    float  maxp = fmaxf(cur, EPSV);
    double e_x  = (double)T_DIM - scm / (double)maxp;

    size_t BC = (size_t)B_DIM * C_DIM;
    size_t o  = (size_t)b * C_DIM + c;
    out[1 + o]          = (float)arg;   // idx
    out[1 + BC + o]     = maxp;         // max_probs
    out[1 + 2 * BC + o] = (float)e_x;   // e_x
}

// ---------------------------------------------------------------------------
// Kernel 3: fast_loss = mean_b [ -log(maxp[b,lab]) + log(e_x[b,lab]/T + EPS) ]
// Single block, 512 threads (one per b).
// ---------------------------------------------------------------------------
__global__ __launch_bounds__(512) void loss_kernel(
    const int* __restrict__ labels, float* __restrict__ out) {
    __shared__ double part[8];
    int b = threadIdx.x;
    size_t BC = (size_t)B_DIM * C_DIM;

    int    lab  = labels[b];
    float  maxp = out[1 + BC + (size_t)b * C_DIM + lab];
    float  e_x  = out[1 + 2 * BC + (size_t)b * C_DIM + lab];
    double i_x  = (double)e_x / (double)T_DIM;
    double pc   = -log((double)maxp) + log(i_x + 1e-8);

    #pragma unroll
    for (int off = 32; off > 0; off >>= 1)
        pc += __shfl_xor(pc, off, 64);

    if ((threadIdx.x & 63) == 0) part[threadIdx.x >> 6] = pc;
    __syncthreads();
    if (threadIdx.x == 0) {
        double s = 0.0;
        #pragma unroll
        for (int i = 0; i < 8; ++i) s += part[i];
        out[0] = (float)(s / (double)B_DIM);
    }
}

extern "C" void kernel_launch(void* const* d_in, const int* in_sizes, int n_in,
                              void* d_out, int out_size, void* d_ws, size_t ws_size,
                              hipStream_t stream) {
    const float* x      = (const float*)d_in[0];
    const int*   labels = (const int*)d_in[1];
    float*       out    = (float*)d_out;

    float* rm = (float*)d_ws;                 // B*T row maxes
    float* rs = rm + (size_t)B_DIM * T_DIM;   // B*T row sums   (total 1 MB of ws)

    row_stats_kernel<<<(B_DIM * T_DIM) / 4, 256, 0, stream>>>(x, rm, rs);
    time_scan_kernel<<<B_DIM * 2, 256, 0, stream>>>(x, rm, rs, out);
    loss_kernel<<<1, 512, 0, stream>>>(labels, out);
}